// Round 7
// baseline (473.023 us; speedup 1.0000x reference)
//
#include <hip/hip_runtime.h>
#include <math.h>

// B=16, DIM=64, RANK=32, H=W=128, E=4, K=2, BINS=8, FREQ_DIM=64, KS=7
// Round 7: k_combine with zero LDS -- xv[64] in registers, weights via contiguous
// wave-uniform s_loads (r-outer P1 rows, c-outer P2 rows). k_projfreq c-outer with
// pre-transposed P0 (k_transW) for contiguous scalar weight loads.

namespace {

struct cpx { float x, y; };
struct Tw7 { cpx t[7]; };

__device__ __forceinline__ cpx cmul(cpx a, cpx b){ return {a.x*b.x - a.y*b.y, a.x*b.y + a.y*b.x}; }

__device__ __forceinline__ cpx tw(int k, float invN){
  float s, c;
  sincosf(-6.283185307179586f * (float)k * invN, &s, &c);
  return {c, s};
}

__device__ __forceinline__ void init_tw(Tw7 &T, int lane){
  T.t[0] = tw(lane,      1.0f/128.0f);
  T.t[1] = tw(lane & 31, 1.0f/64.0f);
  T.t[2] = tw(lane & 15, 1.0f/32.0f);
  T.t[3] = tw(lane & 7,  1.0f/16.0f);
  T.t[4] = tw(lane & 3,  1.0f/8.0f);
  T.t[5] = tw(lane & 1,  1.0f/4.0f);
  T.t[6] = {1.0f, 0.0f};
}

__device__ __forceinline__ int br6(int l){ return (int)(__brev((unsigned)l) >> 26); }

// 128-pt DIF FFT across one wave: lane holds a=in[l], b=in[l+64].
// Output: a = F[2*br6(l)], b = F[2*br6(l)+1].
__device__ __forceinline__ void fft128(cpx &a, cpx &b, int lane, const Tw7 &T){
  cpx u{a.x + b.x, a.y + b.y};
  cpx v{a.x - b.x, a.y - b.y};
  v = cmul(v, T.t[0]);
  a = u; b = v;
  int s = 1;
  #pragma unroll
  for (int m = 32; m >= 1; m >>= 1, s++){
    float pax = __shfl_xor(a.x, m);
    float pay = __shfl_xor(a.y, m);
    float pbx = __shfl_xor(b.x, m);
    float pby = __shfl_xor(b.y, m);
    cpx w = T.t[s];
    if (lane & m){
      cpx ta{pax - a.x, pay - a.y};
      cpx tb{pbx - b.x, pby - b.y};
      a = cmul(ta, w);
      b = cmul(tb, w);
    } else {
      a.x += pax; a.y += pay;
      b.x += pbx; b.y += pby;
    }
  }
}

// spectrum layout: row j (0..63, col0 packs Nyquist), col i. float2 elements.
#define LIDX(j,i) ((((j) << 7)) | (((i) ^ ((j) & 31)) & 127))
// packed row-FFT storage: pair p (0..63), freq j (0..127)
#define ZIDX(p,j) ((((p) << 7)) | (((j) ^ (p)) & 127))

__device__ __forceinline__ float gelu_exact(float v){
  return 0.5f * v * (1.0f + erff(v * 0.70710678118654752f));
}

__device__ __forceinline__ float silu(float v){
  return v / (1.0f + expf(-v));
}

// ---------------- kernels ----------------

// Fused 2-D rFFT per (b,c) + radial energy partials + xmean. 512 threads.
__global__ __launch_bounds__(512) void k_fft2fwd(const float* __restrict__ x, float2* __restrict__ X,
                                                 float* __restrict__ part_w, float* __restrict__ xmean){
  __shared__ float2 z[8192];
  int bc = blockIdx.x; int t = threadIdx.x;
  int lane = t & 63, wv = t >> 6;
  Tw7 T; init_tw(T, lane);
  const float* img = x + (size_t)bc * 16384;

  // row FFTs, two real rows packed per complex FFT: pair p -> rows 2p, 2p+1
  #pragma unroll 4
  for (int k = 0; k < 8; k++){
    int p = wv*8 + k;
    int h0 = 2*p, h1 = 2*p + 1;
    cpx a{img[h0*128 + lane],      img[h1*128 + lane]};
    cpx b{img[h0*128 + lane + 64], img[h1*128 + lane + 64]};
    fft128(a, b, lane, T);
    int j0 = 2*br6(lane), j1 = j0 + 1;
    z[ZIDX(p,j0)] = make_float2(a.x, a.y);
    z[ZIDX(p,j1)] = make_float2(b.x, b.y);
  }
  __syncthreads();

  // column FFTs: unpack two-rows trick on read; results staged in registers.
  float rax[8], ray[8], rbx[8], rby[8];
  #pragma unroll
  for (int k = 0; k < 8; k++){
    int jj = wv*8 + k;
    int p  = lane >> 1, s = lane & 1;
    int p2 = 32 + p;
    cpx a, b;
    if (jj == 0){
      float2 z0 = z[ZIDX(p,0)],  z64 = z[ZIDX(p,64)];
      float2 w0 = z[ZIDX(p2,0)], w64 = z[ZIDX(p2,64)];
      a = { s ? z0.y : z0.x, s ? z64.y : z64.x };
      b = { s ? w0.y : w0.x, s ? w64.y : w64.x };
    } else {
      int jm = 128 - jj;
      float2 z1 = z[ZIDX(p,jj)],  z2 = z[ZIDX(p,jm)];
      if (s == 0) a = { 0.5f*(z1.x + z2.x), 0.5f*(z1.y - z2.y) };
      else        a = { 0.5f*(z1.y + z2.y), 0.5f*(z2.x - z1.x) };
      float2 w1 = z[ZIDX(p2,jj)], w2 = z[ZIDX(p2,jm)];
      if (s == 0) b = { 0.5f*(w1.x + w2.x), 0.5f*(w1.y - w2.y) };
      else        b = { 0.5f*(w1.y + w2.y), 0.5f*(w2.x - w1.x) };
    }
    fft128(a, b, lane, T);
    rax[k] = a.x; ray[k] = a.y; rbx[k] = b.x; rby[k] = b.y;
  }
  __syncthreads();
  #pragma unroll
  for (int k = 0; k < 8; k++){
    int jj = wv*8 + k;
    int i0 = 2*br6(lane);
    z[LIDX(jj,i0)]   = make_float2(rax[k], ray[k]);
    z[LIDX(jj,i0+1)] = make_float2(rbx[k], rby[k]);
  }
  __syncthreads();

  if (t == 0) xmean[bc] = z[LIDX(0,0)].x * (1.0f/16384.0f);

  // radial energy
  float edges[9];
  float step = sqrtf(8192.0f) * 0.125f;
  #pragma unroll
  for (int k = 0; k <= 8; k++) edges[k] = step * (float)k;
  float acc[8] = {0,0,0,0,0,0,0,0};
  for (int idx = t; idx < 64*128; idx += 512){
    int j = idx >> 7, i = idx & 127;
    if (j == 0){
      float2 c0 = z[LIDX(0,i)];
      int in_ = (128 - i) & 127;
      float2 d0v = z[LIDX(0,in_)];
      float x0r = 0.5f*(c0.x + d0v.x), x0i = 0.5f*(c0.y - d0v.y);
      float x6r = 0.5f*(c0.y + d0v.y), x6i = 0.5f*(d0v.x - c0.x);
      float m0 = sqrtf(x0r*x0r + x0i*x0i) * (1.0f/16384.0f);
      float m6 = sqrtf(x6r*x6r + x6i*x6i) * (1.0f/16384.0f);
      float dyv = (float)(i - 64);
      float d0 = sqrtf(dyv*dyv + 4096.0f);
      float d6 = fabsf(dyv);
      #pragma unroll
      for (int k = 0; k < 8; k++){
        if (d0 >= edges[k] && d0 < edges[k+1]) acc[k] += m0;
        if (d6 >= edges[k] && d6 < edges[k+1]) acc[k] += m6;
      }
    } else {
      float2 zv = z[LIDX(j,i)];
      float mag = sqrtf(zv.x*zv.x + zv.y*zv.y) * (2.0f/16384.0f);
      float dy = (float)(i - 64), dx = (float)(j - 64);
      float d = sqrtf(dy*dy + dx*dx);
      #pragma unroll
      for (int k = 0; k < 8; k++)
        if (d >= edges[k] && d < edges[k+1]) acc[k] += mag;
    }
  }
  #pragma unroll
  for (int k = 0; k < 8; k++){
    float v = acc[k];
    for (int off = 32; off > 0; off >>= 1) v += __shfl_xor(v, off);
    if (lane == 0) part_w[(bc*8 + wv)*8 + k] = v;
  }

  // coalesced X write-out
  float2* Xo = X + (size_t)bc * (65*128);
  for (int idx = t; idx < 65*128; idx += 512){
    int j = idx >> 7, i = idx & 127;
    float2 v;
    if (j == 0){
      float2 c0 = z[LIDX(0,i)];
      int in_ = (128 - i) & 127;
      float2 d0v = z[LIDX(0,in_)];
      v = make_float2(0.5f*(c0.x + d0v.x), 0.5f*(c0.y - d0v.y));
    } else if (j == 64){
      float2 c0 = z[LIDX(0,i)];
      int in_ = (128 - i) & 127;
      float2 d0v = z[LIDX(0,in_)];
      v = make_float2(0.5f*(c0.y + d0v.y), 0.5f*(d0v.x - c0.x));
    } else {
      v = z[LIDX(j,i)];
    }
    Xo[idx] = v;
  }
}

__global__ __launch_bounds__(128) void k_routing(const float* __restrict__ xmean, const float* __restrict__ part_w,
    const float* __restrict__ noise, const float* __restrict__ gate_w,
    const float* __restrict__ fg_w1, const float* __restrict__ fg_b1, const float* __restrict__ fg_w2,
    int* __restrict__ slot_e, int* __restrict__ slot_of, float* __restrict__ slot_g){
  __shared__ float femb[16][8];
  __shared__ float hid[16][64];
  __shared__ float lgt[16][4];
  int t = threadIdx.x;
  {
    int b = t >> 3, k = t & 7;
    float s = 0.f;
    for (int c = 0; c < 64; c++)
      for (int w = 0; w < 8; w++)
        s += part_w[((b*64 + c)*8 + w)*8 + k];
    femb[b][k] = s * (1.0f/64.0f);
  }
  __syncthreads();
  for (int idx = t; idx < 16*64; idx += 128){
    int b = idx >> 6, f = idx & 63;
    float s = fg_b1[f];
    for (int k = 0; k < 8; k++) s += femb[b][k] * fg_w1[f*8 + k];
    hid[b][f] = fmaxf(s, 0.f);
  }
  __syncthreads();
  if (t < 64){
    int b = t >> 2, e = t & 3;
    float s = 0.f;
    for (int c = 0; c < 64; c++) s += xmean[b*64 + c] * gate_w[e*64 + c];
    for (int f = 0; f < 64; f++) s += hid[b][f] * fg_w2[e*64 + f];
    lgt[b][e] = s + noise[b*4 + e] * 0.25f;   // NOISE_STD = 1/E
  }
  __syncthreads();
  if (t < 16){
    int b = t;
    float m = fmaxf(fmaxf(lgt[b][0], lgt[b][1]), fmaxf(lgt[b][2], lgt[b][3]));
    float p[4]; float sum = 0.f;
    for (int e = 0; e < 4; e++){ p[e] = expf(lgt[b][e] - m); sum += p[e]; }
    for (int e = 0; e < 4; e++) p[e] /= sum;
    int i1 = 0;
    for (int e = 1; e < 4; e++) if (p[e] > p[i1]) i1 = e;   // ties -> lowest idx (lax.top_k)
    int i2 = -1;
    for (int e = 0; e < 4; e++){ if (e == i1) continue; if (i2 < 0 || p[e] > p[i2]) i2 = e; }
    slot_e[b*2 + 0] = i1;
    slot_e[b*2 + 1] = i2;
    slot_g[b*2 + 0] = p[i1];
    slot_g[b*2 + 1] = p[i2];
    for (int e = 0; e < 4; e++) slot_of[b*4 + e] = (e == i1) ? 0 : ((e == i2) ? 1 : -1);
  }
}

// transpose proj0 for the two freq experts: p0t[s][c][r], s = e>>1 (e in {0,2})
__global__ __launch_bounds__(256) void k_transW(const float* __restrict__ proj0, float* __restrict__ p0t){
  int t = threadIdx.x;
  for (int idx = t; idx < 2048; idx += 256){
    int r = idx >> 6, c = idx & 63;
    p0t[0*2048 + c*32 + r] = proj0[0*2048 + idx];
    p0t[1*2048 + c*32 + r] = proj0[2*2048 + idx];
  }
}

// Both freq experts in one pass over X; weights via contiguous wave-uniform s_loads
// from pre-transposed p0t. Wave w owns rows w*8..w*8+7; lane = i offset (64 i's).
__global__ __launch_bounds__(256) void k_projfreq(const float2* __restrict__ X, const float* __restrict__ p0t,
    float2* __restrict__ Y, const int* __restrict__ slot_e,
    const float* __restrict__ hg_gain, const float* __restrict__ hg_decay,
    const float* __restrict__ lg_gain, const float* __restrict__ lg_decay){
  int b = blockIdx.z;
  int e0 = __builtin_amdgcn_readfirstlane(slot_e[b*2 + 0]);
  int e1 = __builtin_amdgcn_readfirstlane(slot_e[b*2 + 1]);
  bool f0 = (e0 == 0) || (e0 == 2);
  bool f1 = (e1 == 0) || (e1 == 2);
  if (!f0 && !f1) return;
  int j = blockIdx.y;
  int i0 = blockIdx.x * 64;
  int t = threadIdx.x;
  int lane = t & 63;
  int w = __builtin_amdgcn_readfirstlane(t >> 6);
  __shared__ float2 sx[64][64];
  for (int idx = t; idx < 4096; idx += 256){
    int c = idx >> 6, ii = idx & 63;
    sx[c][ii] = X[(((size_t)(b*64 + c))*65 + j)*128 + i0 + ii];
  }
  __syncthreads();
  int i = i0 + lane;
  const float* W0 = p0t + ((f0 ? (e0 >> 1) : (e1 >> 1)) * 2048) + w*8;
  const float* W1 = p0t + ((f1 ? (e1 >> 1) : (e0 >> 1)) * 2048) + w*8;
  float a0x[8] = {0,0,0,0,0,0,0,0}, a0y[8] = {0,0,0,0,0,0,0,0};
  float a1x[8] = {0,0,0,0,0,0,0,0}, a1y[8] = {0,0,0,0,0,0,0,0};
  for (int c = 0; c < 64; c++){
    float2 xv = sx[c][lane];
    const float* wc0 = W0 + c*32;
    const float* wc1 = W1 + c*32;
    #pragma unroll
    for (int k = 0; k < 8; k++){
      float w0v = wc0[k];                 // contiguous 8 dwords, wave-uniform -> s_load_dwordx8
      a0x[k] += w0v * xv.x; a0y[k] += w0v * xv.y;
      float w1v = wc1[k];
      a1x[k] += w1v * xv.x; a1y[k] += w1v * xv.y;
    }
  }
  float fy = (float)(i < 64 ? i : i - 128) * (1.0f/128.0f);
  float fx = (float)j * (1.0f/128.0f);
  float fg = sqrtf(fy*fy + fx*fx);
  if (f0){
    float gain, decay, cmax;
    if (e0 == 0){ gain = *hg_gain; decay = *hg_decay; cmax = 3.0f; }
    else        { gain = *lg_gain; decay = *lg_decay; cmax = 1.0f; }
    float filt = (1.0f - expf(-gain*fg)) * expf(-decay*fg);
    filt = fminf(fmaxf(filt, 0.0f), cmax) * (1.0f/16384.0f);
    int bs = b*2 + 0;
    #pragma unroll
    for (int k = 0; k < 8; k++){
      int r = w*8 + k;
      Y[((size_t)(bs*32 + r))*8320 + j*128 + i] = make_float2(a0x[k]*filt, a0y[k]*filt);
    }
  }
  if (f1){
    float gain, decay, cmax;
    if (e1 == 0){ gain = *hg_gain; decay = *hg_decay; cmax = 3.0f; }
    else        { gain = *lg_gain; decay = *lg_decay; cmax = 1.0f; }
    float filt = (1.0f - expf(-gain*fg)) * expf(-decay*fg);
    filt = fminf(fmaxf(filt, 0.0f), cmax) * (1.0f/16384.0f);
    int bs = b*2 + 1;
    #pragma unroll
    for (int k = 0; k < 8; k++){
      int r = w*8 + k;
      Y[((size_t)(bs*32 + r))*8320 + j*128 + i] = make_float2(a1x[k]*filt, a1y[k]*filt);
    }
  }
}

// Fused inverse 2-D FFT per (bs,r) for freq slots; body written IN PLACE. 512 threads.
__global__ __launch_bounds__(512) void k_ifft2(float2* __restrict__ Y, const int* __restrict__ slot_e){
  int blk = blockIdx.x;
  int bs = blk >> 5, r = blk & 31;
  int es = slot_e[bs];
  if (es == 1 || es == 3) return;     // conv slots skip
  __shared__ float2 z[8192];
  int t = threadIdx.x; int lane = t & 63, wv = t >> 6;
  Tw7 T; init_tw(T, lane);
  float2* Yb = Y + (size_t)(bs*32 + r) * 8320;

  // load; row 0 packed: P[i] = Y[0][i] + i*Y[64][i]
  for (int idx = t; idx < 8192; idx += 512){
    int j = idx >> 7, i = idx & 127;
    if (j == 0){
      float2 y0 = Yb[i];
      float2 y6 = Yb[8192 + i];
      z[LIDX(0,i)] = make_float2(y0.x - y6.y, y0.y + y6.x);
    } else {
      z[LIDX(j,i)] = Yb[idx];
    }
  }
  __syncthreads();

  // inverse column FFTs (unnormalized), in place per column
  #pragma unroll
  for (int k = 0; k < 8; k++){
    int jj = wv*8 + k;
    float2 z0 = z[LIDX(jj,lane)], z1 = z[LIDX(jj,lane+64)];
    cpx a{z0.x, -z0.y}, b{z1.x, -z1.y};
    fft128(a, b, lane, T);
    int i0 = 2*br6(lane);
    z[LIDX(jj,i0)]   = make_float2(a.x, -a.y);
    z[LIDX(jj,i0+1)] = make_float2(b.x, -b.y);
  }
  __syncthreads();

  // inverse row transform: two real output rows per complex inverse FFT
  float* body = (float*)Yb;
  #pragma unroll 2
  for (int k = 0; k < 8; k++){
    int p = wv*8 + k;
    int h = 2*p, h1 = 2*p + 1;
    cpx a, b;
    if (lane == 0){
      float2 c0 = z[LIDX(0,h)], c1 = z[LIDX(0,h1)];
      a = { c0.x, c1.x };
      b = { c0.y, c1.y };
    } else {
      float2 yh = z[LIDX(lane,h)], y1 = z[LIDX(lane,h1)];
      a = { yh.x - y1.y, yh.y + y1.x };
      int lm = 64 - lane;
      float2 zh = z[LIDX(lm,h)], z1_ = z[LIDX(lm,h1)];
      b = { zh.x + z1_.y, z1_.x - zh.y };
    }
    a.y = -a.y; b.y = -b.y;        // conj
    fft128(a, b, lane, T);
    int n0 = 2*br6(lane);
    body[h*128 + n0]      = a.x;   // conj on output: real part
    body[h1*128 + n0]     = -a.y;
    body[h*128 + n0 + 1]  = b.x;
    body[h1*128 + n0 + 1] = -b.y;
  }
}

// A[bs][r] = P0[e_s] x[b]  for conv slots only (weight rows contiguous -> s_load ok).
__global__ __launch_bounds__(256) void k_projA(const float* __restrict__ x, const float* __restrict__ proj0,
    const int* __restrict__ slot_e, float* __restrict__ A){
  int b = blockIdx.y;
  int e0 = slot_e[b*2 + 0], e1 = slot_e[b*2 + 1];
  bool c0 = (e0 == 1) || (e0 == 3);
  bool c1 = (e1 == 1) || (e1 == 3);
  if (!c0 && !c1) return;
  int hw = blockIdx.x * 256 + threadIdx.x;
  const float* xb = x + (size_t)b*64*16384 + hw;
  float xv[64];
  #pragma unroll
  for (int c = 0; c < 64; c++) xv[c] = xb[(size_t)c*16384];
  if (c0){
    const float* W = proj0 + __builtin_amdgcn_readfirstlane(e0)*2048;
    float* Ab = A + (size_t)(b*2 + 0)*32*16384 + hw;
    #pragma unroll 4
    for (int r = 0; r < 32; r++){
      float a = 0.f;
      #pragma unroll
      for (int c = 0; c < 64; c++) a += W[r*64 + c] * xv[c];
      Ab[(size_t)r*16384] = a;
    }
  }
  if (c1){
    const float* W = proj0 + __builtin_amdgcn_readfirstlane(e1)*2048;
    float* Ab = A + (size_t)(b*2 + 1)*32*16384 + hw;
    #pragma unroll 4
    for (int r = 0; r < 32; r++){
      float a = 0.f;
      #pragma unroll
      for (int c = 0; c < 64; c++) a += W[r*64 + c] * xv[c];
      Ab[(size_t)r*16384] = a;
    }
  }
}

// Expert 1 fused: dw3 -> gelu -> dw3, LDS-tiled (16 out rows x 128)
__global__ __launch_bounds__(256) void k_conv3(const float* __restrict__ A, float* __restrict__ bodyY,
    const float* __restrict__ w1g, const float* __restrict__ b1g,
    const float* __restrict__ w2g, const float* __restrict__ b2g,
    const int* __restrict__ slot_of){
  int by = blockIdx.y; int b = by >> 5, r = by & 31;
  int slot = slot_of[b*4 + 1];
  if (slot < 0) return;
  int bs = b*2 + slot;
  int h0 = blockIdx.x * 16;
  int t = threadIdx.x;
  __shared__ float sin_[20*130];
  __shared__ float st[18*130];
  for (int i = t; i < 20*130; i += 256) sin_[i] = 0.f;
  for (int i = t; i < 18*130; i += 256) st[i] = 0.f;
  float w1[9], w2[9];
  #pragma unroll
  for (int k = 0; k < 9; k++){ w1[k] = w1g[r*9 + k]; w2[k] = w2g[r*9 + k]; }
  float b1 = b1g[r], b2 = b2g[r];
  __syncthreads();
  const float* ip = A + (size_t)(bs*32 + r)*16384;
  for (int idx = t; idx < 20*128; idx += 256){
    int li = idx >> 7, ww = idx & 127;
    int ih = h0 - 2 + li;
    if (ih >= 0 && ih < 128) sin_[li*130 + 1 + ww] = ip[ih*128 + ww];
  }
  __syncthreads();
  for (int idx = t; idx < 18*128; idx += 256){
    int li = idx >> 7, ww = idx & 127;
    int hs = h0 - 1 + li;
    if (hs >= 0 && hs < 128){
      float acc = b1;
      #pragma unroll
      for (int kh = 0; kh < 3; kh++)
        #pragma unroll
        for (int kw = 0; kw < 3; kw++)
          acc += w1[kh*3 + kw] * sin_[(li + kh)*130 + ww + kw];
      st[li*130 + 1 + ww] = gelu_exact(acc);
    }
  }
  __syncthreads();
  float* op = bodyY + (size_t)(bs*32 + r)*16640;
  for (int idx = t; idx < 16*128; idx += 256){
    int li = idx >> 7, ww = idx & 127;
    int ho = h0 + li;
    float acc = b2;
    #pragma unroll
    for (int kh = 0; kh < 3; kh++)
      #pragma unroll
      for (int kw = 0; kw < 3; kw++)
        acc += w2[kh*3 + kw] * st[(li + kh)*130 + ww + kw];
    op[ho*128 + ww] = acc;
  }
}

// Expert 3 fused: dw7 -> gelu -> avgpool3 (count_include_pad)
__global__ __launch_bounds__(256) void k_conv7(const float* __restrict__ A, float* __restrict__ bodyY,
    const float* __restrict__ wg, const float* __restrict__ bg,
    const int* __restrict__ slot_of){
  int by = blockIdx.y; int b = by >> 5, r = by & 31;
  int slot = slot_of[b*4 + 3];
  if (slot < 0) return;
  int bs = b*2 + slot;
  int h0 = blockIdx.x * 16;
  int t = threadIdx.x;
  __shared__ float sin_[24*134];
  __shared__ float st[18*134];
  __shared__ float wsh[49];
  for (int i = t; i < 24*134; i += 256) sin_[i] = 0.f;
  for (int i = t; i < 18*134; i += 256) st[i] = 0.f;
  if (t < 49) wsh[t] = wg[r*49 + t];
  float bias = bg[r];
  __syncthreads();
  const float* ip = A + (size_t)(bs*32 + r)*16384;
  for (int idx = t; idx < 24*128; idx += 256){
    int li = idx >> 7, ww = idx & 127;
    int ih = h0 - 4 + li;
    if (ih >= 0 && ih < 128) sin_[li*134 + 3 + ww] = ip[ih*128 + ww];
  }
  __syncthreads();
  for (int idx = t; idx < 18*128; idx += 256){
    int li = idx >> 7, ww = idx & 127;
    int hs = h0 - 1 + li;
    if (hs >= 0 && hs < 128){
      float acc = bias;
      #pragma unroll
      for (int kh = 0; kh < 7; kh++)
        #pragma unroll
        for (int kw = 0; kw < 7; kw++)
          acc += wsh[kh*7 + kw] * sin_[(li + kh)*134 + ww + kw];
      st[li*134 + 1 + ww] = gelu_exact(acc);
    }
  }
  __syncthreads();
  float* op = bodyY + (size_t)(bs*32 + r)*16640;
  for (int idx = t; idx < 16*128; idx += 256){
    int li = idx >> 7, ww = idx & 127;
    int ho = h0 + li;
    float acc = 0.f;
    #pragma unroll
    for (int kh = 0; kh < 3; kh++)
      #pragma unroll
      for (int kw = 0; kw < 3; kw++)
        acc += st[(li + kh)*134 + ww + kw];
    op[ho*128 + ww] = acc * (1.0f/9.0f);
  }
}

// Final: out[b,c] = (g0+g1)*x[b,c] + sum_s g_s * P2[e_s][c,:] (body_s * silu(P1[e_s] x))
// Zero LDS: xv[64] in registers; weights via contiguous wave-uniform s_loads.
__global__ __launch_bounds__(256) void k_combine(const float* __restrict__ x, const float* __restrict__ bodyY,
    const float* __restrict__ proj1, const float* __restrict__ proj2,
    const int* __restrict__ slot_e, const float* __restrict__ slot_g,
    float* __restrict__ out){
  int b = blockIdx.y;
  int t = threadIdx.x;
  int hw = blockIdx.x * 256 + t;
  int ea = __builtin_amdgcn_readfirstlane(slot_e[b*2 + 0]);
  int eb = __builtin_amdgcn_readfirstlane(slot_e[b*2 + 1]);
  float ga = slot_g[b*2 + 0], gb = slot_g[b*2 + 1];
  float gs = ga + gb;
  const float* xb = x + (size_t)b*64*16384 + hw;
  float xv[64];
  #pragma unroll
  for (int c = 0; c < 64; c++) xv[c] = xb[(size_t)c*16384];

  const float* P1a = proj1 + ea*2048;
  const float* P1b = proj1 + eb*2048;
  const float* Ba = bodyY + (size_t)(b*2 + 0)*32*16640 + hw;
  const float* Bb = bodyY + (size_t)(b*2 + 1)*32*16640 + hw;
  float sa[32], sb[32];
  #pragma unroll 4
  for (int r = 0; r < 32; r++){
    const float* wr = P1a + r*64;       // contiguous row -> s_load_dwordx16 chain
    float acc = 0.f;
    #pragma unroll
    for (int c = 0; c < 64; c++) acc += wr[c] * xv[c];
    sa[r] = Ba[(size_t)r*16640] * silu(acc);
  }
  #pragma unroll 4
  for (int r = 0; r < 32; r++){
    const float* wr = P1b + r*64;
    float acc = 0.f;
    #pragma unroll
    for (int c = 0; c < 64; c++) acc += wr[c] * xv[c];
    sb[r] = Bb[(size_t)r*16640] * silu(acc);
  }
  const float* P2a = proj2 + ea*2048;
  const float* P2b = proj2 + eb*2048;
  float* ob = out + (size_t)b*64*16384 + hw;
  #pragma unroll 2
  for (int c = 0; c < 64; c++){
    const float* wca = P2a + c*32;      // contiguous 32 dwords
    const float* wcb = P2b + c*32;
    float acc0 = 0.f, acc1 = 0.f;
    #pragma unroll
    for (int r = 0; r < 32; r++){
      acc0 += wca[r] * sa[r];
      acc1 += wcb[r] * sb[r];
    }
    ob[(size_t)c*16384] = gs*xv[c] + ga*acc0 + gb*acc1;
  }
}

} // namespace

extern "C" void kernel_launch(void* const* d_in, const int* in_sizes, int n_in,
                              void* d_out, int out_size, void* d_ws, size_t ws_size,
                              hipStream_t stream) {
  (void)in_sizes; (void)n_in; (void)out_size; (void)ws_size;
  const float* x        = (const float*)d_in[0];
  const float* noise    = (const float*)d_in[1];
  const float* gate_w   = (const float*)d_in[2];
  const float* fg_w1    = (const float*)d_in[3];
  const float* fg_b1    = (const float*)d_in[4];
  const float* fg_w2    = (const float*)d_in[5];
  const float* proj0    = (const float*)d_in[6];
  const float* proj1    = (const float*)d_in[7];
  const float* proj2    = (const float*)d_in[8];
  const float* hg_gain  = (const float*)d_in[9];
  const float* hg_decay = (const float*)d_in[10];
  const float* hf_w1    = (const float*)d_in[11];
  const float* hf_b1    = (const float*)d_in[12];
  const float* hf_w2    = (const float*)d_in[13];
  const float* hf_b2    = (const float*)d_in[14];
  const float* lg_gain  = (const float*)d_in[15];
  const float* lg_decay = (const float*)d_in[16];
  const float* lf_w     = (const float*)d_in[17];
  const float* lf_b     = (const float*)d_in[18];
  float* out = (float*)d_out;

  // ws (floats):
  //  [0, 17039360)            X spectra [1024][65][128] f2 ; later overlaid by A [32 bs][32 r][16384]
  //  [17039360, 34078720)     Yspec/body [32 bs][32 r][65*128 f2]
  //  tail: xmean 1024 | part_w 65536 | p0t 4096 | slot_g 32 | slot_e 32 (int) | slot_of 64 (int)
  float* ws = (float*)d_ws;
  float2* X  = (float2*)ws;
  float*  A  = ws;
  float*  Yf = ws + 17039360;
  float2* Y2 = (float2*)Yf;
  float*  tail   = ws + 34078720;
  float*  xmean  = tail;
  float*  part_w = xmean + 1024;
  float*  p0t    = part_w + 65536;
  float*  slot_g = p0t + 4096;
  int*    slot_e = (int*)(slot_g + 32);
  int*    slot_of = slot_e + 32;

  // routing inputs (xmean from spectrum DC); weight transpose is independent
  k_transW<<<1, 256, 0, stream>>>(proj0, p0t);
  k_fft2fwd<<<1024, 512, 0, stream>>>(x, X, part_w, xmean);
  k_routing<<<1, 128, 0, stream>>>(xmean, part_w, noise, gate_w, fg_w1, fg_b1, fg_w2,
                                   slot_e, slot_of, slot_g);

  // frequency-domain projections, both freq experts in one X pass
  k_projfreq<<<dim3(2,65,16), 256, 0, stream>>>(X, p0t, Y2, slot_e,
                                                hg_gain, hg_decay, lg_gain, lg_decay);

  // A for conv slots (overlays X; X dead after projfreq)
  k_projA<<<dim3(64,16), 256, 0, stream>>>(x, proj0, slot_e, A);

  // inverse FFTs for freq slots (bodies in place in Yspec)
  k_ifft2<<<1024, 512, 0, stream>>>(Y2, slot_e);

  // conv experts (bodies into Yspec slots)
  k_conv3<<<dim3(8,512), 256, 0, stream>>>(A, Yf, hf_w1, hf_b1, hf_w2, hf_b2, slot_of);
  k_conv7<<<dim3(8,512), 256, 0, stream>>>(A, Yf, lf_w, lf_b, slot_of);

  // final combine (includes shortcut and gating; writes out exactly once)
  k_combine<<<dim3(64,16), 256, 0, stream>>>(x, Yf, proj1, proj2, slot_e, slot_g, out);
}

// Round 8
// 449.381 us; speedup vs baseline: 1.0526x; 1.0526x over previous
//
#include <hip/hip_runtime.h>
#include <math.h>

// B=16, DIM=64, RANK=32, H=W=128, E=4, K=2, BINS=8, FREQ_DIM=64, KS=7
// Round 8: k_combine redesigned to fit the ~80-VGPR allocator budget:
// c-outer phase1 with pre-transposed P1 (contiguous wave-uniform s_loads),
// x re-read (L2-hot) in phase2 instead of xv[64] registers. No spill.

namespace {

struct cpx { float x, y; };
struct Tw7 { cpx t[7]; };

__device__ __forceinline__ cpx cmul(cpx a, cpx b){ return {a.x*b.x - a.y*b.y, a.x*b.y + a.y*b.x}; }

__device__ __forceinline__ cpx tw(int k, float invN){
  float s, c;
  sincosf(-6.283185307179586f * (float)k * invN, &s, &c);
  return {c, s};
}

__device__ __forceinline__ void init_tw(Tw7 &T, int lane){
  T.t[0] = tw(lane,      1.0f/128.0f);
  T.t[1] = tw(lane & 31, 1.0f/64.0f);
  T.t[2] = tw(lane & 15, 1.0f/32.0f);
  T.t[3] = tw(lane & 7,  1.0f/16.0f);
  T.t[4] = tw(lane & 3,  1.0f/8.0f);
  T.t[5] = tw(lane & 1,  1.0f/4.0f);
  T.t[6] = {1.0f, 0.0f};
}

__device__ __forceinline__ int br6(int l){ return (int)(__brev((unsigned)l) >> 26); }

// 128-pt DIF FFT across one wave: lane holds a=in[l], b=in[l+64].
// Output: a = F[2*br6(l)], b = F[2*br6(l)+1].
__device__ __forceinline__ void fft128(cpx &a, cpx &b, int lane, const Tw7 &T){
  cpx u{a.x + b.x, a.y + b.y};
  cpx v{a.x - b.x, a.y - b.y};
  v = cmul(v, T.t[0]);
  a = u; b = v;
  int s = 1;
  #pragma unroll
  for (int m = 32; m >= 1; m >>= 1, s++){
    float pax = __shfl_xor(a.x, m);
    float pay = __shfl_xor(a.y, m);
    float pbx = __shfl_xor(b.x, m);
    float pby = __shfl_xor(b.y, m);
    cpx w = T.t[s];
    if (lane & m){
      cpx ta{pax - a.x, pay - a.y};
      cpx tb{pbx - b.x, pby - b.y};
      a = cmul(ta, w);
      b = cmul(tb, w);
    } else {
      a.x += pax; a.y += pay;
      b.x += pbx; b.y += pby;
    }
  }
}

// spectrum layout: row j (0..63, col0 packs Nyquist), col i. float2 elements.
#define LIDX(j,i) ((((j) << 7)) | (((i) ^ ((j) & 31)) & 127))
// packed row-FFT storage: pair p (0..63), freq j (0..127)
#define ZIDX(p,j) ((((p) << 7)) | (((j) ^ (p)) & 127))

__device__ __forceinline__ float gelu_exact(float v){
  return 0.5f * v * (1.0f + erff(v * 0.70710678118654752f));
}

__device__ __forceinline__ float silu(float v){
  return v / (1.0f + expf(-v));
}

// ---------------- kernels ----------------

// Fused 2-D rFFT per (b,c) + radial energy partials + xmean. 512 threads.
__global__ __launch_bounds__(512) void k_fft2fwd(const float* __restrict__ x, float2* __restrict__ X,
                                                 float* __restrict__ part_w, float* __restrict__ xmean){
  __shared__ float2 z[8192];
  int bc = blockIdx.x; int t = threadIdx.x;
  int lane = t & 63, wv = t >> 6;
  Tw7 T; init_tw(T, lane);
  const float* img = x + (size_t)bc * 16384;

  // row FFTs, two real rows packed per complex FFT: pair p -> rows 2p, 2p+1
  #pragma unroll 4
  for (int k = 0; k < 8; k++){
    int p = wv*8 + k;
    int h0 = 2*p, h1 = 2*p + 1;
    cpx a{img[h0*128 + lane],      img[h1*128 + lane]};
    cpx b{img[h0*128 + lane + 64], img[h1*128 + lane + 64]};
    fft128(a, b, lane, T);
    int j0 = 2*br6(lane), j1 = j0 + 1;
    z[ZIDX(p,j0)] = make_float2(a.x, a.y);
    z[ZIDX(p,j1)] = make_float2(b.x, b.y);
  }
  __syncthreads();

  // column FFTs: unpack two-rows trick on read; results staged in registers.
  float rax[8], ray[8], rbx[8], rby[8];
  #pragma unroll
  for (int k = 0; k < 8; k++){
    int jj = wv*8 + k;
    int p  = lane >> 1, s = lane & 1;
    int p2 = 32 + p;
    cpx a, b;
    if (jj == 0){
      float2 z0 = z[ZIDX(p,0)],  z64 = z[ZIDX(p,64)];
      float2 w0 = z[ZIDX(p2,0)], w64 = z[ZIDX(p2,64)];
      a = { s ? z0.y : z0.x, s ? z64.y : z64.x };
      b = { s ? w0.y : w0.x, s ? w64.y : w64.x };
    } else {
      int jm = 128 - jj;
      float2 z1 = z[ZIDX(p,jj)],  z2 = z[ZIDX(p,jm)];
      if (s == 0) a = { 0.5f*(z1.x + z2.x), 0.5f*(z1.y - z2.y) };
      else        a = { 0.5f*(z1.y + z2.y), 0.5f*(z2.x - z1.x) };
      float2 w1 = z[ZIDX(p2,jj)], w2 = z[ZIDX(p2,jm)];
      if (s == 0) b = { 0.5f*(w1.x + w2.x), 0.5f*(w1.y - w2.y) };
      else        b = { 0.5f*(w1.y + w2.y), 0.5f*(w2.x - w1.x) };
    }
    fft128(a, b, lane, T);
    rax[k] = a.x; ray[k] = a.y; rbx[k] = b.x; rby[k] = b.y;
  }
  __syncthreads();
  #pragma unroll
  for (int k = 0; k < 8; k++){
    int jj = wv*8 + k;
    int i0 = 2*br6(lane);
    z[LIDX(jj,i0)]   = make_float2(rax[k], ray[k]);
    z[LIDX(jj,i0+1)] = make_float2(rbx[k], rby[k]);
  }
  __syncthreads();

  if (t == 0) xmean[bc] = z[LIDX(0,0)].x * (1.0f/16384.0f);

  // radial energy
  float edges[9];
  float step = sqrtf(8192.0f) * 0.125f;
  #pragma unroll
  for (int k = 0; k <= 8; k++) edges[k] = step * (float)k;
  float acc[8] = {0,0,0,0,0,0,0,0};
  for (int idx = t; idx < 64*128; idx += 512){
    int j = idx >> 7, i = idx & 127;
    if (j == 0){
      float2 c0 = z[LIDX(0,i)];
      int in_ = (128 - i) & 127;
      float2 d0v = z[LIDX(0,in_)];
      float x0r = 0.5f*(c0.x + d0v.x), x0i = 0.5f*(c0.y - d0v.y);
      float x6r = 0.5f*(c0.y + d0v.y), x6i = 0.5f*(d0v.x - c0.x);
      float m0 = sqrtf(x0r*x0r + x0i*x0i) * (1.0f/16384.0f);
      float m6 = sqrtf(x6r*x6r + x6i*x6i) * (1.0f/16384.0f);
      float dyv = (float)(i - 64);
      float d0 = sqrtf(dyv*dyv + 4096.0f);
      float d6 = fabsf(dyv);
      #pragma unroll
      for (int k = 0; k < 8; k++){
        if (d0 >= edges[k] && d0 < edges[k+1]) acc[k] += m0;
        if (d6 >= edges[k] && d6 < edges[k+1]) acc[k] += m6;
      }
    } else {
      float2 zv = z[LIDX(j,i)];
      float mag = sqrtf(zv.x*zv.x + zv.y*zv.y) * (2.0f/16384.0f);
      float dy = (float)(i - 64), dx = (float)(j - 64);
      float d = sqrtf(dy*dy + dx*dx);
      #pragma unroll
      for (int k = 0; k < 8; k++)
        if (d >= edges[k] && d < edges[k+1]) acc[k] += mag;
    }
  }
  #pragma unroll
  for (int k = 0; k < 8; k++){
    float v = acc[k];
    for (int off = 32; off > 0; off >>= 1) v += __shfl_xor(v, off);
    if (lane == 0) part_w[(bc*8 + wv)*8 + k] = v;
  }

  // coalesced X write-out
  float2* Xo = X + (size_t)bc * (65*128);
  for (int idx = t; idx < 65*128; idx += 512){
    int j = idx >> 7, i = idx & 127;
    float2 v;
    if (j == 0){
      float2 c0 = z[LIDX(0,i)];
      int in_ = (128 - i) & 127;
      float2 d0v = z[LIDX(0,in_)];
      v = make_float2(0.5f*(c0.x + d0v.x), 0.5f*(c0.y - d0v.y));
    } else if (j == 64){
      float2 c0 = z[LIDX(0,i)];
      int in_ = (128 - i) & 127;
      float2 d0v = z[LIDX(0,in_)];
      v = make_float2(0.5f*(c0.y + d0v.y), 0.5f*(d0v.x - c0.x));
    } else {
      v = z[LIDX(j,i)];
    }
    Xo[idx] = v;
  }
}

__global__ __launch_bounds__(128) void k_routing(const float* __restrict__ xmean, const float* __restrict__ part_w,
    const float* __restrict__ noise, const float* __restrict__ gate_w,
    const float* __restrict__ fg_w1, const float* __restrict__ fg_b1, const float* __restrict__ fg_w2,
    int* __restrict__ slot_e, int* __restrict__ slot_of, float* __restrict__ slot_g){
  __shared__ float femb[16][8];
  __shared__ float hid[16][64];
  __shared__ float lgt[16][4];
  int t = threadIdx.x;
  {
    int b = t >> 3, k = t & 7;
    float s = 0.f;
    for (int c = 0; c < 64; c++)
      for (int w = 0; w < 8; w++)
        s += part_w[((b*64 + c)*8 + w)*8 + k];
    femb[b][k] = s * (1.0f/64.0f);
  }
  __syncthreads();
  for (int idx = t; idx < 16*64; idx += 128){
    int b = idx >> 6, f = idx & 63;
    float s = fg_b1[f];
    for (int k = 0; k < 8; k++) s += femb[b][k] * fg_w1[f*8 + k];
    hid[b][f] = fmaxf(s, 0.f);
  }
  __syncthreads();
  if (t < 64){
    int b = t >> 2, e = t & 3;
    float s = 0.f;
    for (int c = 0; c < 64; c++) s += xmean[b*64 + c] * gate_w[e*64 + c];
    for (int f = 0; f < 64; f++) s += hid[b][f] * fg_w2[e*64 + f];
    lgt[b][e] = s + noise[b*4 + e] * 0.25f;   // NOISE_STD = 1/E
  }
  __syncthreads();
  if (t < 16){
    int b = t;
    float m = fmaxf(fmaxf(lgt[b][0], lgt[b][1]), fmaxf(lgt[b][2], lgt[b][3]));
    float p[4]; float sum = 0.f;
    for (int e = 0; e < 4; e++){ p[e] = expf(lgt[b][e] - m); sum += p[e]; }
    for (int e = 0; e < 4; e++) p[e] /= sum;
    int i1 = 0;
    for (int e = 1; e < 4; e++) if (p[e] > p[i1]) i1 = e;   // ties -> lowest idx (lax.top_k)
    int i2 = -1;
    for (int e = 0; e < 4; e++){ if (e == i1) continue; if (i2 < 0 || p[e] > p[i2]) i2 = e; }
    slot_e[b*2 + 0] = i1;
    slot_e[b*2 + 1] = i2;
    slot_g[b*2 + 0] = p[i1];
    slot_g[b*2 + 1] = p[i2];
    for (int e = 0; e < 4; e++) slot_of[b*4 + e] = (e == i1) ? 0 : ((e == i2) ? 1 : -1);
  }
}

// transposes: p0t[s][c][r] for freq experts (s=e>>1, e in {0,2}); p1t[e][c][r] all experts.
__global__ __launch_bounds__(256) void k_transW(const float* __restrict__ proj0, const float* __restrict__ proj1,
                                                float* __restrict__ p0t, float* __restrict__ p1t){
  int t = threadIdx.x;
  for (int idx = t; idx < 2048; idx += 256){
    int r = idx >> 6, c = idx & 63;
    p0t[0*2048 + c*32 + r] = proj0[0*2048 + idx];
    p0t[1*2048 + c*32 + r] = proj0[2*2048 + idx];
    p1t[0*2048 + c*32 + r] = proj1[0*2048 + idx];
    p1t[1*2048 + c*32 + r] = proj1[1*2048 + idx];
    p1t[2*2048 + c*32 + r] = proj1[2*2048 + idx];
    p1t[3*2048 + c*32 + r] = proj1[3*2048 + idx];
  }
}

// Both freq experts in one pass over X; weights via contiguous wave-uniform s_loads
// from pre-transposed p0t. Wave w owns rows w*8..w*8+7; lane = i offset (64 i's).
__global__ __launch_bounds__(256) void k_projfreq(const float2* __restrict__ X, const float* __restrict__ p0t,
    float2* __restrict__ Y, const int* __restrict__ slot_e,
    const float* __restrict__ hg_gain, const float* __restrict__ hg_decay,
    const float* __restrict__ lg_gain, const float* __restrict__ lg_decay){
  int b = blockIdx.z;
  int e0 = __builtin_amdgcn_readfirstlane(slot_e[b*2 + 0]);
  int e1 = __builtin_amdgcn_readfirstlane(slot_e[b*2 + 1]);
  bool f0 = (e0 == 0) || (e0 == 2);
  bool f1 = (e1 == 0) || (e1 == 2);
  if (!f0 && !f1) return;
  int j = blockIdx.y;
  int i0 = blockIdx.x * 64;
  int t = threadIdx.x;
  int lane = t & 63;
  int w = __builtin_amdgcn_readfirstlane(t >> 6);
  __shared__ float2 sx[64][64];
  for (int idx = t; idx < 4096; idx += 256){
    int c = idx >> 6, ii = idx & 63;
    sx[c][ii] = X[(((size_t)(b*64 + c))*65 + j)*128 + i0 + ii];
  }
  __syncthreads();
  int i = i0 + lane;
  const float* W0 = p0t + ((f0 ? (e0 >> 1) : (e1 >> 1)) * 2048) + w*8;
  const float* W1 = p0t + ((f1 ? (e1 >> 1) : (e0 >> 1)) * 2048) + w*8;
  float a0x[8] = {0,0,0,0,0,0,0,0}, a0y[8] = {0,0,0,0,0,0,0,0};
  float a1x[8] = {0,0,0,0,0,0,0,0}, a1y[8] = {0,0,0,0,0,0,0,0};
  for (int c = 0; c < 64; c++){
    float2 xv = sx[c][lane];
    const float* wc0 = W0 + c*32;
    const float* wc1 = W1 + c*32;
    #pragma unroll
    for (int k = 0; k < 8; k++){
      float w0v = wc0[k];                 // contiguous 8 dwords, wave-uniform -> s_load
      a0x[k] += w0v * xv.x; a0y[k] += w0v * xv.y;
      float w1v = wc1[k];
      a1x[k] += w1v * xv.x; a1y[k] += w1v * xv.y;
    }
  }
  float fy = (float)(i < 64 ? i : i - 128) * (1.0f/128.0f);
  float fx = (float)j * (1.0f/128.0f);
  float fg = sqrtf(fy*fy + fx*fx);
  if (f0){
    float gain, decay, cmax;
    if (e0 == 0){ gain = *hg_gain; decay = *hg_decay; cmax = 3.0f; }
    else        { gain = *lg_gain; decay = *lg_decay; cmax = 1.0f; }
    float filt = (1.0f - expf(-gain*fg)) * expf(-decay*fg);
    filt = fminf(fmaxf(filt, 0.0f), cmax) * (1.0f/16384.0f);
    int bs = b*2 + 0;
    #pragma unroll
    for (int k = 0; k < 8; k++){
      int r = w*8 + k;
      Y[((size_t)(bs*32 + r))*8320 + j*128 + i] = make_float2(a0x[k]*filt, a0y[k]*filt);
    }
  }
  if (f1){
    float gain, decay, cmax;
    if (e1 == 0){ gain = *hg_gain; decay = *hg_decay; cmax = 3.0f; }
    else        { gain = *lg_gain; decay = *lg_decay; cmax = 1.0f; }
    float filt = (1.0f - expf(-gain*fg)) * expf(-decay*fg);
    filt = fminf(fmaxf(filt, 0.0f), cmax) * (1.0f/16384.0f);
    int bs = b*2 + 1;
    #pragma unroll
    for (int k = 0; k < 8; k++){
      int r = w*8 + k;
      Y[((size_t)(bs*32 + r))*8320 + j*128 + i] = make_float2(a1x[k]*filt, a1y[k]*filt);
    }
  }
}

// Fused inverse 2-D FFT per (bs,r) for freq slots; body written IN PLACE. 512 threads.
__global__ __launch_bounds__(512) void k_ifft2(float2* __restrict__ Y, const int* __restrict__ slot_e){
  int blk = blockIdx.x;
  int bs = blk >> 5, r = blk & 31;
  int es = slot_e[bs];
  if (es == 1 || es == 3) return;     // conv slots skip
  __shared__ float2 z[8192];
  int t = threadIdx.x; int lane = t & 63, wv = t >> 6;
  Tw7 T; init_tw(T, lane);
  float2* Yb = Y + (size_t)(bs*32 + r) * 8320;

  // load; row 0 packed: P[i] = Y[0][i] + i*Y[64][i]
  for (int idx = t; idx < 8192; idx += 512){
    int j = idx >> 7, i = idx & 127;
    if (j == 0){
      float2 y0 = Yb[i];
      float2 y6 = Yb[8192 + i];
      z[LIDX(0,i)] = make_float2(y0.x - y6.y, y0.y + y6.x);
    } else {
      z[LIDX(j,i)] = Yb[idx];
    }
  }
  __syncthreads();

  // inverse column FFTs (unnormalized), in place per column
  #pragma unroll
  for (int k = 0; k < 8; k++){
    int jj = wv*8 + k;
    float2 z0 = z[LIDX(jj,lane)], z1 = z[LIDX(jj,lane+64)];
    cpx a{z0.x, -z0.y}, b{z1.x, -z1.y};
    fft128(a, b, lane, T);
    int i0 = 2*br6(lane);
    z[LIDX(jj,i0)]   = make_float2(a.x, -a.y);
    z[LIDX(jj,i0+1)] = make_float2(b.x, -b.y);
  }
  __syncthreads();

  // inverse row transform: two real output rows per complex inverse FFT
  float* body = (float*)Yb;
  #pragma unroll 2
  for (int k = 0; k < 8; k++){
    int p = wv*8 + k;
    int h = 2*p, h1 = 2*p + 1;
    cpx a, b;
    if (lane == 0){
      float2 c0 = z[LIDX(0,h)], c1 = z[LIDX(0,h1)];
      a = { c0.x, c1.x };
      b = { c0.y, c1.y };
    } else {
      float2 yh = z[LIDX(lane,h)], y1 = z[LIDX(lane,h1)];
      a = { yh.x - y1.y, yh.y + y1.x };
      int lm = 64 - lane;
      float2 zh = z[LIDX(lm,h)], z1_ = z[LIDX(lm,h1)];
      b = { zh.x + z1_.y, z1_.x - zh.y };
    }
    a.y = -a.y; b.y = -b.y;        // conj
    fft128(a, b, lane, T);
    int n0 = 2*br6(lane);
    body[h*128 + n0]      = a.x;   // conj on output: real part
    body[h1*128 + n0]     = -a.y;
    body[h*128 + n0 + 1]  = b.x;
    body[h1*128 + n0 + 1] = -b.y;
  }
}

// A[bs][r] = P0[e_s] x[b]  for conv slots only (weight rows contiguous -> s_load ok).
__global__ __launch_bounds__(256) void k_projA(const float* __restrict__ x, const float* __restrict__ proj0,
    const int* __restrict__ slot_e, float* __restrict__ A){
  int b = blockIdx.y;
  int e0 = slot_e[b*2 + 0], e1 = slot_e[b*2 + 1];
  bool c0 = (e0 == 1) || (e0 == 3);
  bool c1 = (e1 == 1) || (e1 == 3);
  if (!c0 && !c1) return;
  int hw = blockIdx.x * 256 + threadIdx.x;
  const float* xb = x + (size_t)b*64*16384 + hw;
  float xv[64];
  #pragma unroll
  for (int c = 0; c < 64; c++) xv[c] = xb[(size_t)c*16384];
  if (c0){
    const float* W = proj0 + __builtin_amdgcn_readfirstlane(e0)*2048;
    float* Ab = A + (size_t)(b*2 + 0)*32*16384 + hw;
    #pragma unroll 4
    for (int r = 0; r < 32; r++){
      float a = 0.f;
      #pragma unroll
      for (int c = 0; c < 64; c++) a += W[r*64 + c] * xv[c];
      Ab[(size_t)r*16384] = a;
    }
  }
  if (c1){
    const float* W = proj0 + __builtin_amdgcn_readfirstlane(e1)*2048;
    float* Ab = A + (size_t)(b*2 + 1)*32*16384 + hw;
    #pragma unroll 4
    for (int r = 0; r < 32; r++){
      float a = 0.f;
      #pragma unroll
      for (int c = 0; c < 64; c++) a += W[r*64 + c] * xv[c];
      Ab[(size_t)r*16384] = a;
    }
  }
}

// Expert 1 fused: dw3 -> gelu -> dw3, LDS-tiled (16 out rows x 128)
__global__ __launch_bounds__(256) void k_conv3(const float* __restrict__ A, float* __restrict__ bodyY,
    const float* __restrict__ w1g, const float* __restrict__ b1g,
    const float* __restrict__ w2g, const float* __restrict__ b2g,
    const int* __restrict__ slot_of){
  int by = blockIdx.y; int b = by >> 5, r = by & 31;
  int slot = slot_of[b*4 + 1];
  if (slot < 0) return;
  int bs = b*2 + slot;
  int h0 = blockIdx.x * 16;
  int t = threadIdx.x;
  __shared__ float sin_[20*130];
  __shared__ float st[18*130];
  for (int i = t; i < 20*130; i += 256) sin_[i] = 0.f;
  for (int i = t; i < 18*130; i += 256) st[i] = 0.f;
  float w1[9], w2[9];
  #pragma unroll
  for (int k = 0; k < 9; k++){ w1[k] = w1g[r*9 + k]; w2[k] = w2g[r*9 + k]; }
  float b1 = b1g[r], b2 = b2g[r];
  __syncthreads();
  const float* ip = A + (size_t)(bs*32 + r)*16384;
  for (int idx = t; idx < 20*128; idx += 256){
    int li = idx >> 7, ww = idx & 127;
    int ih = h0 - 2 + li;
    if (ih >= 0 && ih < 128) sin_[li*130 + 1 + ww] = ip[ih*128 + ww];
  }
  __syncthreads();
  for (int idx = t; idx < 18*128; idx += 256){
    int li = idx >> 7, ww = idx & 127;
    int hs = h0 - 1 + li;
    if (hs >= 0 && hs < 128){
      float acc = b1;
      #pragma unroll
      for (int kh = 0; kh < 3; kh++)
        #pragma unroll
        for (int kw = 0; kw < 3; kw++)
          acc += w1[kh*3 + kw] * sin_[(li + kh)*130 + ww + kw];
      st[li*130 + 1 + ww] = gelu_exact(acc);
    }
  }
  __syncthreads();
  float* op = bodyY + (size_t)(bs*32 + r)*16640;
  for (int idx = t; idx < 16*128; idx += 256){
    int li = idx >> 7, ww = idx & 127;
    int ho = h0 + li;
    float acc = b2;
    #pragma unroll
    for (int kh = 0; kh < 3; kh++)
      #pragma unroll
      for (int kw = 0; kw < 3; kw++)
        acc += w2[kh*3 + kw] * st[(li + kh)*130 + ww + kw];
    op[ho*128 + ww] = acc;
  }
}

// Expert 3 fused: dw7 -> gelu -> avgpool3 (count_include_pad)
__global__ __launch_bounds__(256) void k_conv7(const float* __restrict__ A, float* __restrict__ bodyY,
    const float* __restrict__ wg, const float* __restrict__ bg,
    const int* __restrict__ slot_of){
  int by = blockIdx.y; int b = by >> 5, r = by & 31;
  int slot = slot_of[b*4 + 3];
  if (slot < 0) return;
  int bs = b*2 + slot;
  int h0 = blockIdx.x * 16;
  int t = threadIdx.x;
  __shared__ float sin_[24*134];
  __shared__ float st[18*134];
  __shared__ float wsh[49];
  for (int i = t; i < 24*134; i += 256) sin_[i] = 0.f;
  for (int i = t; i < 18*134; i += 256) st[i] = 0.f;
  if (t < 49) wsh[t] = wg[r*49 + t];
  float bias = bg[r];
  __syncthreads();
  const float* ip = A + (size_t)(bs*32 + r)*16384;
  for (int idx = t; idx < 24*128; idx += 256){
    int li = idx >> 7, ww = idx & 127;
    int ih = h0 - 4 + li;
    if (ih >= 0 && ih < 128) sin_[li*134 + 3 + ww] = ip[ih*128 + ww];
  }
  __syncthreads();
  for (int idx = t; idx < 18*128; idx += 256){
    int li = idx >> 7, ww = idx & 127;
    int hs = h0 - 1 + li;
    if (hs >= 0 && hs < 128){
      float acc = bias;
      #pragma unroll
      for (int kh = 0; kh < 7; kh++)
        #pragma unroll
        for (int kw = 0; kw < 7; kw++)
          acc += wsh[kh*7 + kw] * sin_[(li + kh)*134 + ww + kw];
      st[li*134 + 1 + ww] = gelu_exact(acc);
    }
  }
  __syncthreads();
  float* op = bodyY + (size_t)(bs*32 + r)*16640;
  for (int idx = t; idx < 16*128; idx += 256){
    int li = idx >> 7, ww = idx & 127;
    int ho = h0 + li;
    float acc = 0.f;
    #pragma unroll
    for (int kh = 0; kh < 3; kh++)
      #pragma unroll
      for (int kw = 0; kw < 3; kw++)
        acc += st[(li + kh)*134 + ww + kw];
    op[ho*128 + ww] = acc * (1.0f/9.0f);
  }
}

// Final: out[b,c] = (g0+g1)*x[b,c] + sum_s g_s * P2[e_s][c,:] (body_s * silu(P1[e_s] x))
// c-outer both phases; weights contiguous wave-uniform (p1t transposed, P2 natural).
// Live regs: sa[32]+sb[32]+temps (~70) -- fits the allocator's ~80-VGPR budget.
__global__ __launch_bounds__(256) void k_combine(const float* __restrict__ x, const float* __restrict__ bodyY,
    const float* __restrict__ p1t, const float* __restrict__ proj2,
    const int* __restrict__ slot_e, const float* __restrict__ slot_g,
    float* __restrict__ out){
  int b = blockIdx.y;
  int t = threadIdx.x;
  int hw = blockIdx.x * 256 + t;
  int ea = __builtin_amdgcn_readfirstlane(slot_e[b*2 + 0]);
  int eb = __builtin_amdgcn_readfirstlane(slot_e[b*2 + 1]);
  float ga = slot_g[b*2 + 0], gb = slot_g[b*2 + 1];
  float gs = ga + gb;
  const float* xb = x + (size_t)b*64*16384 + hw;
  const float* W1a = p1t + ea*2048;
  const float* W1b = p1t + eb*2048;

  float sa[32], sb[32];
  #pragma unroll
  for (int r = 0; r < 32; r++){ sa[r] = 0.f; sb[r] = 0.f; }
  #pragma unroll 2
  for (int c = 0; c < 64; c++){
    float xc = xb[(size_t)c*16384];
    const float* wa = W1a + c*32;       // contiguous 32 dwords, wave-uniform -> s_load
    const float* wb = W1b + c*32;
    #pragma unroll
    for (int r = 0; r < 32; r++){
      sa[r] += wa[r] * xc;
      sb[r] += wb[r] * xc;
    }
  }
  // G -> body * silu(G)
  const float* Ba = bodyY + (size_t)(b*2 + 0)*32*16640 + hw;
  const float* Bb = bodyY + (size_t)(b*2 + 1)*32*16640 + hw;
  #pragma unroll
  for (int r = 0; r < 32; r++){
    sa[r] = Ba[(size_t)r*16640] * silu(sa[r]);
    sb[r] = Bb[(size_t)r*16640] * silu(sb[r]);
  }
  const float* P2a = proj2 + ea*2048;
  const float* P2b = proj2 + eb*2048;
  float* ob = out + (size_t)b*64*16384 + hw;
  #pragma unroll 2
  for (int c = 0; c < 64; c++){
    float xc = xb[(size_t)c*16384];     // L1/L2-hot re-read
    const float* wca = P2a + c*32;      // contiguous 32 dwords
    const float* wcb = P2b + c*32;
    float acc0 = 0.f, acc1 = 0.f;
    #pragma unroll
    for (int r = 0; r < 32; r++){
      acc0 += wca[r] * sa[r];
      acc1 += wcb[r] * sb[r];
    }
    ob[(size_t)c*16384] = gs*xc + ga*acc0 + gb*acc1;
  }
}

} // namespace

extern "C" void kernel_launch(void* const* d_in, const int* in_sizes, int n_in,
                              void* d_out, int out_size, void* d_ws, size_t ws_size,
                              hipStream_t stream) {
  (void)in_sizes; (void)n_in; (void)out_size; (void)ws_size;
  const float* x        = (const float*)d_in[0];
  const float* noise    = (const float*)d_in[1];
  const float* gate_w   = (const float*)d_in[2];
  const float* fg_w1    = (const float*)d_in[3];
  const float* fg_b1    = (const float*)d_in[4];
  const float* fg_w2    = (const float*)d_in[5];
  const float* proj0    = (const float*)d_in[6];
  const float* proj1    = (const float*)d_in[7];
  const float* proj2    = (const float*)d_in[8];
  const float* hg_gain  = (const float*)d_in[9];
  const float* hg_decay = (const float*)d_in[10];
  const float* hf_w1    = (const float*)d_in[11];
  const float* hf_b1    = (const float*)d_in[12];
  const float* hf_w2    = (const float*)d_in[13];
  const float* hf_b2    = (const float*)d_in[14];
  const float* lg_gain  = (const float*)d_in[15];
  const float* lg_decay = (const float*)d_in[16];
  const float* lf_w     = (const float*)d_in[17];
  const float* lf_b     = (const float*)d_in[18];
  float* out = (float*)d_out;

  // ws (floats):
  //  [0, 17039360)            X spectra [1024][65][128] f2 ; later overlaid by A [32 bs][32 r][16384]
  //  [17039360, 34078720)     Yspec/body [32 bs][32 r][65*128 f2]
  //  tail: xmean 1024 | part_w 65536 | p0t 4096 | p1t 8192 | slot_g 32 | slot_e 32 (int) | slot_of 64 (int)
  float* ws = (float*)d_ws;
  float2* X  = (float2*)ws;
  float*  A  = ws;
  float*  Yf = ws + 17039360;
  float2* Y2 = (float2*)Yf;
  float*  tail   = ws + 34078720;
  float*  xmean  = tail;
  float*  part_w = xmean + 1024;
  float*  p0t    = part_w + 65536;
  float*  p1t    = p0t + 4096;
  float*  slot_g = p1t + 8192;
  int*    slot_e = (int*)(slot_g + 32);
  int*    slot_of = slot_e + 32;

  // routing inputs (xmean from spectrum DC); weight transposes independent
  k_transW<<<1, 256, 0, stream>>>(proj0, proj1, p0t, p1t);
  k_fft2fwd<<<1024, 512, 0, stream>>>(x, X, part_w, xmean);
  k_routing<<<1, 128, 0, stream>>>(xmean, part_w, noise, gate_w, fg_w1, fg_b1, fg_w2,
                                   slot_e, slot_of, slot_g);

  // frequency-domain projections, both freq experts in one X pass
  k_projfreq<<<dim3(2,65,16), 256, 0, stream>>>(X, p0t, Y2, slot_e,
                                                hg_gain, hg_decay, lg_gain, lg_decay);

  // A for conv slots (overlays X; X dead after projfreq)
  k_projA<<<dim3(64,16), 256, 0, stream>>>(x, proj0, slot_e, A);

  // inverse FFTs for freq slots (bodies in place in Yspec)
  k_ifft2<<<1024, 512, 0, stream>>>(Y2, slot_e);

  // conv experts (bodies into Yspec slots)
  k_conv3<<<dim3(8,512), 256, 0, stream>>>(A, Yf, hf_w1, hf_b1, hf_w2, hf_b2, slot_of);
  k_conv7<<<dim3(8,512), 256, 0, stream>>>(A, Yf, lf_w, lf_b, slot_of);

  // final combine (includes shortcut and gating; writes out exactly once)
  k_combine<<<dim3(64,16), 256, 0, stream>>>(x, Yf, p1t, proj2, slot_e, slot_g, out);
}